// Round 4
// baseline (206.721 us; speedup 1.0000x reference)
//
#include <hip/hip_runtime.h>

// Median blur 3x3, replicate borders, NHWC fp32 [B, 512, 512, 3].
// med9 = med3( max3(row mins), med3(row meds), min3(row maxes) )
// R3 = R2 with compile fix: nontemporal store goes through a clang
// ext_vector_type(4) (the builtin rejects HIP_vector_type<float,4>).
// One thread per output float4-group: 9 independent dwordx4 loads
// (3 rows x 3 blocks) -> combine -> 1 nontemporal dwordx4 store.

#define IMG_H 512
#define IMG_W 512
#define IMG_C 3
#define ROW_F (IMG_W * IMG_C)   // 1536 floats per row
#define NGROUPS (ROW_F / 4)     // 384 float4-groups per row

typedef float floatx4 __attribute__((ext_vector_type(4)));

__device__ __forceinline__ float med3f(float a, float b, float c) {
    return __builtin_amdgcn_fmed3f(a, b, c);
}
__device__ __forceinline__ float min3f(float a, float b, float c) {
    return fminf(fminf(a, b), c);
}
__device__ __forceinline__ float max3f(float a, float b, float c) {
    return fmaxf(fmaxf(a, b), c);
}

__device__ __forceinline__ float4 min3v(float4 a, float4 b, float4 c) {
    return make_float4(min3f(a.x,b.x,c.x), min3f(a.y,b.y,c.y),
                       min3f(a.z,b.z,c.z), min3f(a.w,b.w,c.w));
}
__device__ __forceinline__ float4 med3v(float4 a, float4 b, float4 c) {
    return make_float4(med3f(a.x,b.x,c.x), med3f(a.y,b.y,c.y),
                       med3f(a.z,b.z,c.z), med3f(a.w,b.w,c.w));
}
__device__ __forceinline__ float4 max3v(float4 a, float4 b, float4 c) {
    return make_float4(max3f(a.x,b.x,c.x), max3f(a.y,b.y,c.y),
                       max3f(a.z,b.z,c.z), max3f(a.w,b.w,c.w));
}

__global__ __launch_bounds__(128) void median3x3_kernel(
        const float* __restrict__ in, float* __restrict__ out) {
    const int g = blockIdx.x * blockDim.x + threadIdx.x;   // 0..383
    const int h = blockIdx.y;                              // 0..511
    const int b = blockIdx.z;

    const bool left_edge  = (g == 0);
    const bool right_edge = (g == NGROUPS - 1);

    const int hm = (h == 0)         ? 0 : h - 1;
    const int hp = (h == IMG_H - 1) ? h : h + 1;

    const float* base = in + (size_t)b * IMG_H * ROW_F + (size_t)g * 4;
    const float* p0 = base + (size_t)hm * ROW_F;
    const float* p1 = base + (size_t)h  * ROW_F;
    const float* p2 = base + (size_t)hp * ROW_F;

    // Issue all 9 loads up front, fully independent -> max MLP.
    const float4 m0 = *(const float4*)p0;
    const float4 m1 = *(const float4*)p1;
    const float4 m2 = *(const float4*)p2;
    float4 l0, l1, l2, r0, r1, r2;
    if (!left_edge) {
        const float4 a0 = *(const float4*)(p0 - 4);
        const float4 a1 = *(const float4*)(p1 - 4);
        const float4 a2 = *(const float4*)(p2 - 4);
        l0 = make_float4(a0.y, a0.z, a0.w, m0.x);
        l1 = make_float4(a1.y, a1.z, a1.w, m1.x);
        l2 = make_float4(a2.y, a2.z, a2.w, m2.x);
    } else {
        // floats 0..3 of the row: w = 0,0,0,1 -> left = replicate ch of w=0
        l0 = make_float4(m0.x, m0.y, m0.z, m0.x);
        l1 = make_float4(m1.x, m1.y, m1.z, m1.x);
        l2 = make_float4(m2.x, m2.y, m2.z, m2.x);
    }
    if (!right_edge) {
        const float4 c0 = *(const float4*)(p0 + 4);
        const float4 c1 = *(const float4*)(p1 + 4);
        const float4 c2 = *(const float4*)(p2 + 4);
        r0 = make_float4(m0.w, c0.x, c0.y, c0.z);
        r1 = make_float4(m1.w, c1.x, c1.y, c1.z);
        r2 = make_float4(m2.w, c2.x, c2.y, c2.z);
    } else {
        // floats 1532..1535: w = 510,511,511,511 -> right replicates w=511
        r0 = make_float4(m0.w, m0.y, m0.z, m0.w);
        r1 = make_float4(m1.w, m1.y, m1.z, m1.w);
        r2 = make_float4(m2.w, m2.y, m2.z, m2.w);
    }

    const float4 mn0 = min3v(l0, m0, r0), md0 = med3v(l0, m0, r0), mx0 = max3v(l0, m0, r0);
    const float4 mn1 = min3v(l1, m1, r1), md1 = med3v(l1, m1, r1), mx1 = max3v(l1, m1, r1);
    const float4 mn2 = min3v(l2, m2, r2), md2 = med3v(l2, m2, r2), mx2 = max3v(l2, m2, r2);

    const float4 A  = max3v(mn0, mn1, mn2);
    const float4 Bm = med3v(md0, md1, md2);
    const float4 Cm = min3v(mx0, mx1, mx2);
    const float4 res = med3v(A, Bm, Cm);

    float* op = out + (size_t)b * IMG_H * ROW_F + (size_t)h * ROW_F + (size_t)g * 4;
    floatx4 rv = { res.x, res.y, res.z, res.w };
    __builtin_nontemporal_store(rv, (floatx4*)op);
}

extern "C" void kernel_launch(void* const* d_in, const int* in_sizes, int n_in,
                              void* d_out, int out_size, void* d_ws, size_t ws_size,
                              hipStream_t stream) {
    const float* in = (const float*)d_in[0];
    float* out = (float*)d_out;

    const int B = in_sizes[0] / (IMG_H * ROW_F);   // 32

    dim3 grid(NGROUPS / 128, IMG_H, B);            // (3, 512, 32)
    dim3 block(128, 1, 1);
    median3x3_kernel<<<grid, block, 0, stream>>>(in, out);
}

// Round 5
// 197.221 us; speedup vs baseline: 1.0482x; 1.0482x over previous
//
#include <hip/hip_runtime.h>

// Median blur 3x3, replicate borders, NHWC fp32 [B, 512, 512, 3].
// med9 = med3( max3(row mins), med3(row meds), min3(row maxes) )
// R4: no-reuse max-MLP structure (9 independent dwordx4 loads per thread)
// + XCD-aware block swizzle. Flat 1D grid; xcd = l%8 (HW round-robin),
// within an XCD consecutive blocks walk h for a fixed image, each XCD owns
// 4 of the 32 images. The 3 blocks reading any row are consecutive on the
// SAME XCD -> vertical re-reads hit that XCD's L2; HBM sees compulsory
// traffic only. Block = 384 threads = one full row of float4-groups.

#define IMG_H 512
#define IMG_W 512
#define IMG_C 3
#define ROW_F (IMG_W * IMG_C)   // 1536 floats per row
#define NGROUPS (ROW_F / 4)     // 384 float4-groups per row

typedef float floatx4 __attribute__((ext_vector_type(4)));

__device__ __forceinline__ float med3f(float a, float b, float c) {
    return __builtin_amdgcn_fmed3f(a, b, c);
}
__device__ __forceinline__ float min3f(float a, float b, float c) {
    return fminf(fminf(a, b), c);
}
__device__ __forceinline__ float max3f(float a, float b, float c) {
    return fmaxf(fmaxf(a, b), c);
}

__device__ __forceinline__ float4 min3v(float4 a, float4 b, float4 c) {
    return make_float4(min3f(a.x,b.x,c.x), min3f(a.y,b.y,c.y),
                       min3f(a.z,b.z,c.z), min3f(a.w,b.w,c.w));
}
__device__ __forceinline__ float4 med3v(float4 a, float4 b, float4 c) {
    return make_float4(med3f(a.x,b.x,c.x), med3f(a.y,b.y,c.y),
                       med3f(a.z,b.z,c.z), med3f(a.w,b.w,c.w));
}
__device__ __forceinline__ float4 max3v(float4 a, float4 b, float4 c) {
    return make_float4(max3f(a.x,b.x,c.x), max3f(a.y,b.y,c.y),
                       max3f(a.z,b.z,c.z), max3f(a.w,b.w,c.w));
}

__global__ __launch_bounds__(384) void median3x3_kernel(
        const float* __restrict__ in, float* __restrict__ out) {
    // XCD-aware decode: blocks 8 apart share an XCD's L2 (dispatch is
    // round-robin over 8 XCDs). Walk h sequentially within each XCD.
    const int l   = blockIdx.x;          // 0..16383
    const int xcd = l & 7;
    const int s   = l >> 3;              // 0..2047 per XCD
    const int h   = s & (IMG_H - 1);     // sequential h within the XCD
    const int img = s >> 9;              // 0..3
    const int b   = xcd + 8 * img;       // each XCD owns 4 images

    const int g = threadIdx.x;           // 0..383, one group per thread
    const bool left_edge  = (g == 0);
    const bool right_edge = (g == NGROUPS - 1);

    const int hm = (h == 0)         ? 0 : h - 1;
    const int hp = (h == IMG_H - 1) ? h : h + 1;

    const float* base = in + (size_t)b * IMG_H * ROW_F + (size_t)g * 4;
    const float* p0 = base + (size_t)hm * ROW_F;
    const float* p1 = base + (size_t)h  * ROW_F;
    const float* p2 = base + (size_t)hp * ROW_F;

    // 9 independent loads up front -> max MLP.
    const float4 m0 = *(const float4*)p0;
    const float4 m1 = *(const float4*)p1;
    const float4 m2 = *(const float4*)p2;
    float4 l0, l1, l2, r0, r1, r2;
    if (!left_edge) {
        const float4 a0 = *(const float4*)(p0 - 4);
        const float4 a1 = *(const float4*)(p1 - 4);
        const float4 a2 = *(const float4*)(p2 - 4);
        l0 = make_float4(a0.y, a0.z, a0.w, m0.x);
        l1 = make_float4(a1.y, a1.z, a1.w, m1.x);
        l2 = make_float4(a2.y, a2.z, a2.w, m2.x);
    } else {
        // floats 0..3 of the row: w = 0,0,0,1 -> left replicates w=0
        l0 = make_float4(m0.x, m0.y, m0.z, m0.x);
        l1 = make_float4(m1.x, m1.y, m1.z, m1.x);
        l2 = make_float4(m2.x, m2.y, m2.z, m2.x);
    }
    if (!right_edge) {
        const float4 c0 = *(const float4*)(p0 + 4);
        const float4 c1 = *(const float4*)(p1 + 4);
        const float4 c2 = *(const float4*)(p2 + 4);
        r0 = make_float4(m0.w, c0.x, c0.y, c0.z);
        r1 = make_float4(m1.w, c1.x, c1.y, c1.z);
        r2 = make_float4(m2.w, c2.x, c2.y, c2.z);
    } else {
        // floats 1532..1535: w = 510,511,511,511 -> right replicates w=511
        r0 = make_float4(m0.w, m0.y, m0.z, m0.w);
        r1 = make_float4(m1.w, m1.y, m1.z, m1.w);
        r2 = make_float4(m2.w, m2.y, m2.z, m2.w);
    }

    const float4 mn0 = min3v(l0, m0, r0), md0 = med3v(l0, m0, r0), mx0 = max3v(l0, m0, r0);
    const float4 mn1 = min3v(l1, m1, r1), md1 = med3v(l1, m1, r1), mx1 = max3v(l1, m1, r1);
    const float4 mn2 = min3v(l2, m2, r2), md2 = med3v(l2, m2, r2), mx2 = max3v(l2, m2, r2);

    const float4 A  = max3v(mn0, mn1, mn2);
    const float4 Bm = med3v(md0, md1, md2);
    const float4 Cm = min3v(mx0, mx1, mx2);
    const float4 res = med3v(A, Bm, Cm);

    float* op = out + (size_t)b * IMG_H * ROW_F + (size_t)h * ROW_F + (size_t)g * 4;
    floatx4 rv = { res.x, res.y, res.z, res.w };
    __builtin_nontemporal_store(rv, (floatx4*)op);
}

extern "C" void kernel_launch(void* const* d_in, const int* in_sizes, int n_in,
                              void* d_out, int out_size, void* d_ws, size_t ws_size,
                              hipStream_t stream) {
    const float* in = (const float*)d_in[0];
    float* out = (float*)d_out;

    const int B = in_sizes[0] / (IMG_H * ROW_F);   // 32
    const int nblocks = B * IMG_H;                 // 16384

    median3x3_kernel<<<dim3(nblocks, 1, 1), dim3(384, 1, 1), 0, stream>>>(in, out);
}

// Round 6
// 176.689 us; speedup vs baseline: 1.1700x; 1.1162x over previous
//
#include <hip/hip_runtime.h>

// Median blur 3x3, replicate borders, NHWC fp32 [B, 512, 512, 3].
// med9 = med3( max3(row mins), med3(row meds), min3(row maxes) )
// R5: LDS-staged tile. R0-R4 all plateau at ~17-25 B/cyc/CU of L1 read
// traffic -> the 9x redundant global reads per output are the bottleneck.
// Stage each input byte through L1 once into LDS (tile 64 groups x 8 rows,
// +1 group / +1 row halo), serve the 3x3 neighborhood from LDS (~5x the
// per-CU bandwidth), and pair adjacent output rows per thread so row stats
// (min/med/max) are computed once and shared.

#define IMG_H 512
#define IMG_W 512
#define IMG_C 3
#define ROW_F (IMG_W * IMG_C)   // 1536 floats per row
#define NGROUPS (ROW_F / 4)     // 384 float4-groups per row

#define TW 64                   // tile width in float4-groups (256 floats)
#define TH 8                    // output rows per tile
#define SROWS (TH + 2)          // 10 staged rows
#define SGROUPS (TW + 2)        // 66 staged groups per row (1-group halo each side)
#define STRIDE 268              // LDS row stride in floats (264 + 4 pad)

typedef float floatx4 __attribute__((ext_vector_type(4)));

__device__ __forceinline__ float med3f(float a, float b, float c) {
    return __builtin_amdgcn_fmed3f(a, b, c);
}
__device__ __forceinline__ float min3f(float a, float b, float c) {
    return fminf(fminf(a, b), c);
}
__device__ __forceinline__ float max3f(float a, float b, float c) {
    return fmaxf(fmaxf(a, b), c);
}

__device__ __forceinline__ float4 min3v(float4 a, float4 b, float4 c) {
    return make_float4(min3f(a.x,b.x,c.x), min3f(a.y,b.y,c.y),
                       min3f(a.z,b.z,c.z), min3f(a.w,b.w,c.w));
}
__device__ __forceinline__ float4 med3v(float4 a, float4 b, float4 c) {
    return make_float4(med3f(a.x,b.x,c.x), med3f(a.y,b.y,c.y),
                       med3f(a.z,b.z,c.z), med3f(a.w,b.w,c.w));
}
__device__ __forceinline__ float4 max3v(float4 a, float4 b, float4 c) {
    return make_float4(max3f(a.x,b.x,c.x), max3f(a.y,b.y,c.y),
                       max3f(a.z,b.z,c.z), max3f(a.w,b.w,c.w));
}

__global__ __launch_bounds__(256) void median3x3_kernel(
        const float* __restrict__ in, float* __restrict__ out) {
    __shared__ float lds[SROWS * STRIDE];

    // XCD-aware decode (dispatch is round-robin over 8 XCDs): within an XCD,
    // consecutive blocks walk h-tiles so vertical halo rows hit that XCD's L2.
    // Per XCD: 64 h-tiles x 6 x-tiles x 4 images = 1536 blocks.  (B == 32)
    const int l   = blockIdx.x;           // 0..12287
    const int xcd = l & 7;
    const int s   = l >> 3;               // 0..1535
    const int hy  = s & 63;               // h-tile, fastest
    const int t2  = s >> 6;               // 0..23
    const int bx  = t2 % 6;               // x-tile
    const int img = t2 / 6;               // 0..3
    const int b   = xcd + 8 * img;

    const int h0 = hy * TH;
    const int G0 = bx * TW;

    // ---- Stage (TH+2) x (TW+2) float4-groups into LDS (each byte through
    // L1 exactly once, modulo the 1-row/1-group halo). Addresses clamped at
    // image borders; clamped values are never consumed (edge flags below).
    const float* ibase = in + (size_t)b * IMG_H * ROW_F;
    for (int k = threadIdx.x; k < SROWS * SGROUPS; k += 256) {
        const int rr = k / SGROUPS;
        const int kk = k - rr * SGROUPS;
        int h = h0 - 1 + rr;
        h = (h < 0) ? 0 : ((h > IMG_H - 1) ? IMG_H - 1 : h);
        int gg = G0 - 1 + kk;
        gg = (gg < 0) ? 0 : ((gg > NGROUPS - 1) ? NGROUPS - 1 : gg);
        const float4 v = *(const float4*)(ibase + (size_t)h * ROW_F + (size_t)gg * 4);
        *(float4*)(&lds[rr * STRIDE + kk * 4]) = v;
    }
    __syncthreads();

    // ---- Compute: thread (tx, ty) handles group tx, output rows 2*ty, 2*ty+1.
    // Output row r uses staged rows r, r+1, r+2; the pair shares rows r0+1,
    // r0+2's stats (computed once).
    const int tx = threadIdx.x & 63;
    const int ty = threadIdx.x >> 6;      // 0..3
    const int r0 = ty * 2;                // 0,2,4,6

    const bool left_edge  = (bx == 0 && tx == 0);
    const bool right_edge = (bx == 5 && tx == TW - 1);

    float4 mn[4], md[4], mx[4];
    #pragma unroll
    for (int i = 0; i < 4; ++i) {
        const float* row = &lds[(r0 + i) * STRIDE + (tx + 1) * 4];
        const float4 m = *(const float4*)row;
        float4 lv, rv;
        if (!left_edge) {
            const float4 lb = *(const float4*)(row - 4);
            lv = make_float4(lb.y, lb.z, lb.w, m.x);   // shift by one pixel (3 floats)
        } else {
            // floats 0..3 of the row: w = 0,0,0,1 -> left replicates w=0
            lv = make_float4(m.x, m.y, m.z, m.x);
        }
        if (!right_edge) {
            const float4 rb = *(const float4*)(row + 4);
            rv = make_float4(m.w, rb.x, rb.y, rb.z);
        } else {
            // floats 1532..1535: w = 510,511,511,511 -> right replicates w=511
            rv = make_float4(m.w, m.y, m.z, m.w);
        }
        mn[i] = min3v(lv, m, rv);
        md[i] = med3v(lv, m, rv);
        mx[i] = max3v(lv, m, rv);
    }

    float* obase = out + (size_t)b * IMG_H * ROW_F + (size_t)G0 * 4 + (size_t)tx * 4;
    #pragma unroll
    for (int j = 0; j < 2; ++j) {
        const float4 A  = max3v(mn[j], mn[j+1], mn[j+2]);
        const float4 Bm = med3v(md[j], md[j+1], md[j+2]);
        const float4 Cm = min3v(mx[j], mx[j+1], mx[j+2]);
        const float4 res = med3v(A, Bm, Cm);
        floatx4 rv4 = { res.x, res.y, res.z, res.w };
        __builtin_nontemporal_store(rv4, (floatx4*)(obase + (size_t)(h0 + r0 + j) * ROW_F));
    }
}

extern "C" void kernel_launch(void* const* d_in, const int* in_sizes, int n_in,
                              void* d_out, int out_size, void* d_ws, size_t ws_size,
                              hipStream_t stream) {
    const float* in = (const float*)d_in[0];
    float* out = (float*)d_out;

    const int B = in_sizes[0] / (IMG_H * ROW_F);       // 32
    const int nblocks = B * (IMG_H / TH) * (NGROUPS / TW);   // 12288

    median3x3_kernel<<<dim3(nblocks, 1, 1), dim3(256, 1, 1), 0, stream>>>(in, out);
}